// Round 17
// baseline (543.310 us; speedup 1.0000x reference)
//
#include <hip/hip_runtime.h>
#include <hip/hip_bf16.h>
#include <string.h>
#include <stdint.h>

// Pipeline:
//   k_fused    : gemm1+hopf producer/consumer (R14/R15 PROVEN, verbatim)
//   k_crit_wcvt: critic (4096 blks) + weight split-bf16 conversion (16 blks)
//   k_gemmDm_ld: MFMA gemmD (256 blks, 16t x 64a, K=2048 full) + lD (16 blks)
//   k_epi      : compact-m indexing (no ks partials)
//   k_scan_*   : unchanged
//
// Ledger (razor-margin test: passing absmax 1.25 vs threshold 1.27):
//   R3 hopf 212us; gemm1->hopf recursion numerics BIT-FROZEN (chaotic:
//     R6/R7/R8 trig substitutions all decohered -> 1.5/NaN).
//   R14/R15: fused gemm1+hopf (sc1 stores, relaxed flags) 304us; total 504.
//   R16: gemmD-under-hopf mega-fusion REGRESSED (515; 1024 spinner blocks
//     choked occupancy). Reverted per pre-commit.
//   R17 (this): gemmD is FEED-FORWARD (not part of the chaotic recursion):
//     its errors do not decohere — only shift gpi by ~error magnitude.
//     Split-bf16 weights (hi+lo, ~2^-17 rel err -> gpi err ~1e-3 << 0.02
//     margin); d1c/d2c already exact bf16. MFMA 16x16x32_bf16:
//       C/D: col=lane&15, row=(lane>>4)*4+reg  [m89 HW-verified]
//       A/B: k in {4g..4g+3} u {16+4g..16+4g+3}, g=lane>>4; frag regs
//            0-1 = k-half [0,16), regs 2-3 = [16,32)  [m156/m162 tr-read]
//     m1r=d1r*Wr-d1i*Wi etc via 16 MFMA/K32-step (neg folded into d1i^sign).
//   Fallback: fail => revert to R15 verbatim.

#define T_ 4096
#define D_ 256
#define U_ 2048
#define A_ 64

typedef float f32x4 __attribute__((ext_vector_type(4)));
typedef short bh8 __attribute__((ext_vector_type(8)));
union F8 { uint32_t u[4]; bh8 v; };

__device__ __forceinline__ float bflo(uint32_t p) { return __uint_as_float(p << 16); }
__device__ __forceinline__ float bfhi(uint32_t p) { return __uint_as_float(p & 0xffff0000u); }
__device__ __forceinline__ uint16_t bf16rne(float x) {
  __hip_bfloat16 h = __float2bfloat16(x);
  uint16_t u;
  __builtin_memcpy(&u, &h, 2);
  return u;
}

// ---------------- Hopf step/load macros (R3 structure, PROVEN) -----------
#define HOPF_LOAD(BUF, i, tbase)                                            \
  do {                                                                      \
    const float* bx_ = xc + (size_t)((tbase) + (i)) * (U_ * 2);             \
    asm volatile("global_load_dwordx2 %0, %1, %2"                           \
                 : "=v"(BUF[i])                                             \
                 : "v"(voffx), "s"(bx_));                                   \
  } while (0)

#define HOPF_STEP(BUF, i, tb)                                               \
  do {                                                                      \
    const float xr_ = BUF[i].x, xi_ = BUF[i].y;                             \
    const float f_ = fmaf(xr_, c, xi_ * s);                                 \
    const float g_ = fmaf(xi_, c, -(xr_ * s));                              \
    const float rn_ = fmaf(0.01f, fmaf(r, fmaf(-r, r, 1.0f), f_), r);       \
    const float rinv_ = __builtin_amdgcn_rcpf(fmaxf(r, 1e-6f));             \
    const float phin_ = fmaf(0.01f, g_ * rinv_, phi + dto);                 \
    float cn_, sn_;                                                         \
    __sincosf(phin_, &sn_, &cn_);                                           \
    uint32_t pk_;                                                           \
    asm("v_cvt_pk_bf16_f32 %0, %1, %2"                                     \
        : "=v"(pk_)                                                         \
        : "v"(rn_ * cn_), "v"(rn_ * sn_));                                  \
    const uint32_t* bd_ = dst + (size_t)((tb) + (i)) * U_;                  \
    asm volatile("global_store_dword %0, %1, %2" ::"v"(voffd), "v"(pk_),    \
                 "s"(bd_));                                                  \
    r = rn_; phi = phin_; c = cn_; s = sn_;                                 \
  } while (0)

#define VMWAIT(N)                                  \
  asm volatile("s_waitcnt vmcnt(" #N ")");         \
  __builtin_amdgcn_sched_barrier(0)

#define WAIT_TILE(tt)                                                       \
  do {                                                                      \
    uint32_t rdy_;                                                          \
    for (;;) {                                                              \
      rdy_ = 0u;                                                            \
      if (threadIdx.x == 0)                                                 \
        rdy_ = __hip_atomic_fetch_add(&flags[tt], 0u, __ATOMIC_RELAXED,     \
                                      __HIP_MEMORY_SCOPE_AGENT);            \
      rdy_ = __shfl(rdy_, 0);                                               \
      if (rdy_ >= 32u) break;                                               \
      __builtin_amdgcn_s_sleep(8);                                          \
    }                                                                       \
    __builtin_amdgcn_sched_barrier(0);                                      \
  } while (0)

// ---------------- FUSED gemm1 + hopf (R15 verbatim, PROVEN) --------------
__global__ __launch_bounds__(256) void k_fused(
    const float* __restrict__ S, const float* __restrict__ Wr,
    const float* __restrict__ Wi, const float* __restrict__ br,
    const float* __restrict__ bi, const float* __restrict__ phi1,
    const float* __restrict__ phi2, const float* __restrict__ om1,
    const float* __restrict__ om2, float* __restrict__ xc,
    uint32_t* __restrict__ d1c, uint32_t* __restrict__ d2c,
    uint32_t* __restrict__ flags) {
  const int bid = blockIdx.x;
  if (bid >= 64) {
    // gemm1 role (NUMERICS FROZEN, byte-identical)
    __shared__ float sT[32][68];
    __shared__ float wrT[32][68];
    __shared__ float wiT[32][68];
    const int tid = threadIdx.x;
    const int gb = bid - 64;
    const int t0 = (gb >> 5) * 64;
    const int u0 = (gb & 31) * 64;
    const int un = tid & 15, tm = tid >> 4;
    const int lr = tid >> 3;
    const int lc = (tid & 7) * 4;
    float accR[4][4] = {}, accI[4][4] = {};
    for (int k0 = 0; k0 < D_; k0 += 32) {
      __syncthreads();
#pragma unroll
      for (int p = 0; p < 2; ++p) {
        const int row = p * 32 + lr;
        float4 v = *(const float4*)&S[(size_t)(t0 + row) * D_ + k0 + lc];
        sT[lc + 0][row] = v.x; sT[lc + 1][row] = v.y;
        sT[lc + 2][row] = v.z; sT[lc + 3][row] = v.w;
        float4 a = *(const float4*)&Wr[(size_t)(u0 + row) * D_ + k0 + lc];
        wrT[lc + 0][row] = a.x; wrT[lc + 1][row] = a.y;
        wrT[lc + 2][row] = a.z; wrT[lc + 3][row] = a.w;
        float4 b = *(const float4*)&Wi[(size_t)(u0 + row) * D_ + k0 + lc];
        wiT[lc + 0][row] = b.x; wiT[lc + 1][row] = b.y;
        wiT[lc + 2][row] = b.z; wiT[lc + 3][row] = b.w;
      }
      __syncthreads();
#pragma unroll
      for (int k = 0; k < 32; ++k) {
        const float4 sv = *(const float4*)&sT[k][tm * 4];
        const float4 ar = *(const float4*)&wrT[k][un * 4];
        const float4 ai = *(const float4*)&wiT[k][un * 4];
        const float ss[4] = {sv.x, sv.y, sv.z, sv.w};
        const float wd[4] = {ar.x - ai.x, ar.y - ai.y, ar.z - ai.z, ar.w - ai.w};
        const float wm[4] = {ar.x + ai.x, ar.y + ai.y, ar.z + ai.z, ar.w + ai.w};
#pragma unroll
        for (int i = 0; i < 4; ++i)
#pragma unroll
          for (int j = 0; j < 4; ++j) {
            accR[i][j] = fmaf(ss[i], wd[j], accR[i][j]);
            accI[i][j] = fmaf(ss[i], wm[j], accI[i][j]);
          }
      }
    }
    const float4 brv = *(const float4*)&br[u0 + un * 4];
    const float4 biv = *(const float4*)&bi[u0 + un * 4];
    const float brx[4] = {brv.x, brv.y, brv.z, brv.w};
    const float bix[4] = {biv.x, biv.y, biv.z, biv.w};
#pragma unroll
    for (int i = 0; i < 4; ++i) {
      float vr[4], vi[4];
#pragma unroll
      for (int j = 0; j < 4; ++j) {
        vr[j] = fmaxf(accR[i][j] + brx[j], 0.f);
        vi[j] = fmaxf(accI[i][j] + bix[j], 0.f);
      }
      const size_t base = ((size_t)(t0 + tm * 4 + i) * U_ + u0 + un * 4) * 2;
      f32x4 lo = {vr[0], vi[0], vr[1], vi[1]};
      f32x4 hi = {vr[2], vi[2], vr[3], vi[3]};
      float* p0 = &xc[base];
      float* p1 = &xc[base + 4];
      asm volatile("global_store_dwordx4 %0, %1, off sc1" ::"v"(p0), "v"(lo)
                   : "memory");
      asm volatile("global_store_dwordx4 %0, %1, off sc1" ::"v"(p1), "v"(hi)
                   : "memory");
    }
    asm volatile("s_waitcnt vmcnt(0)");
    __syncthreads();
    if (tid == 0)
      __hip_atomic_fetch_add(&flags[t0 >> 6], 1u, __ATOMIC_RELAXED,
                             __HIP_MEMORY_SCOPE_AGENT);
    return;
  }
  // hopf role
  if (threadIdx.x >= 64) return;
  __builtin_amdgcn_s_setprio(3);
  const int ub = bid & 31;
  const int osc = bid >> 5;
  const int u = ub * 64 + threadIdx.x;
  float phi = (osc ? phi2[u] : phi1[u]) * 0.1f;
  const float omega = osc ? om2[u] : om1[u];
  const uint32_t* __restrict__ dst = (osc ? d2c : d1c);
  const float dto = 0.01f * omega;
  float r = 1.0f;
  float c, s;
  __sincosf(phi, &s, &c);
  const uint32_t voffx = (uint32_t)u * 8u;
  const uint32_t voffd = (uint32_t)u * 4u;

  constexpr int PF = 32;
  float2 bufA[PF], bufB[PF];
  WAIT_TILE(0);
#pragma unroll
  for (int i = 0; i < PF; ++i) HOPF_LOAD(bufA, i, 0);
#pragma unroll
  for (int i = 0; i < PF; ++i) HOPF_LOAD(bufB, i, PF);
  VMWAIT(32);

  for (int t0 = 0; t0 < T_; t0 += 2 * PF) {
#pragma unroll
    for (int i = 0; i < PF; ++i) HOPF_STEP(bufA, i, t0);
    {
      int tp = t0 + 2 * PF;
      if (tp >= T_) tp = 0;
      WAIT_TILE(tp >> 6);
#pragma unroll
      for (int i = 0; i < PF; ++i) HOPF_LOAD(bufA, i, tp);
    }
    VMWAIT(63);
#pragma unroll
    for (int i = 0; i < PF; ++i) HOPF_STEP(bufB, i, t0 + PF);
    {
      int tp = t0 + 3 * PF;
      if (tp >= T_) tp = 0;
#pragma unroll
      for (int i = 0; i < PF; ++i) HOPF_LOAD(bufB, i, tp);
    }
    VMWAIT(63);
  }
  asm volatile("s_waitcnt vmcnt(0)");
  __builtin_amdgcn_s_setprio(0);
}

// ---------------- critic + weight split-bf16 conversion ----------------
__global__ __launch_bounds__(256) void k_crit_wcvt(
    const uint32_t* __restrict__ d1c, const float* __restrict__ cWr,
    const float* __restrict__ cWi, const float* __restrict__ cbr,
    const float* __restrict__ cbi, const float* __restrict__ dpWr,
    const float* __restrict__ dpWi, const float* __restrict__ ipWr,
    const float* __restrict__ ipWi, float* __restrict__ value,
    uint16_t* __restrict__ wc) {
  const int tid = threadIdx.x;
  if (blockIdx.x >= T_) {
    // wcvt role: 16 blocks; split 4 matrices (64x2048) into hi/lo bf16.
    const float* srcs[4] = {dpWr, dpWi, ipWr, ipWi};
    const int g = (blockIdx.x - T_) * 256 + tid;  // 0..4095
#pragma unroll
    for (int mi = 0; mi < 4; ++mi) {
      const float* sp = srcs[mi];
      uint16_t* hi = wc + (size_t)(2 * mi) * 131072;
      uint16_t* lo = wc + (size_t)(2 * mi + 1) * 131072;
      for (int j = 0; j < 32; ++j) {
        const int e = g * 32 + j;
        const float w = sp[e];
        const uint16_t hb = bf16rne(w);
        const float hf = __uint_as_float((uint32_t)hb << 16);
        hi[e] = hb;
        lo[e] = bf16rne(w - hf);
      }
    }
    return;
  }
  const int t = blockIdx.x;
  float vr = 0.f, vi = 0.f;
#pragma unroll
  for (int i = 0; i < 8; ++i) {
    const int uu = i * 256 + tid;
    const uint32_t p = d1c[(size_t)t * U_ + uu];
    const float dr = bflo(p), di = bfhi(p);
    const float wr = cWr[uu], wi = cWi[uu];
    vr = fmaf(dr, wr, fmaf(-di, wi, vr));
    vi = fmaf(dr, wi, fmaf(di, wr, vi));
  }
#pragma unroll
  for (int o = 32; o >= 1; o >>= 1) {
    vr += __shfl_xor(vr, o);
    vi += __shfl_xor(vi, o);
  }
  __shared__ float red[2][4];
  if ((tid & 63) == 0) { red[0][tid >> 6] = vr; red[1][tid >> 6] = vi; }
  __syncthreads();
  if (tid == 0) {
    const float r0 = red[0][0] + red[0][1] + red[0][2] + red[0][3] + cbr[0];
    const float i0 = red[1][0] + red[1][1] + red[1][2] + red[1][3] + cbi[0];
    value[t] = sqrtf(r0 * r0 + i0 * i0);
  }
}

// ---------------- MFMA gemmD (+ lD role) ----------------
// gemmD: 256 blocks, each 16t x 64a, K=2048 full; 4 waves, wave w -> a-cols
// [16w,16w+16). mfma_f32_16x16x32_bf16. A=d (16x32 t x u), B=W^T (32x16).
// Output compact: m[mi][t][a], mi in {m1r,m1i,m2r,m2i}.
#define MFMA_(A, B, C) \
  __builtin_amdgcn_mfma_f32_16x16x32_bf16((A).v, (B).v, (C), 0, 0, 0)

__global__ __launch_bounds__(256) void k_gemmDm_ld(
    const uint32_t* __restrict__ d1c, const uint32_t* __restrict__ d2c,
    const uint16_t* __restrict__ wc, const float* __restrict__ value,
    float* __restrict__ m, float* __restrict__ lD1,
    float* __restrict__ lD2) {
  const int tid = threadIdx.x;
  const int bid = blockIdx.x;
  if (bid >= 256) {
    // lD role: 16 blocks
    const int t = (bid - 256) * 256 + tid;
    const float v = value[t];
    const float pv = (t > 0) ? value[t - 1] : 0.f;
    const float x = 5.0f * (v - pv);
    const float sg = 1.0f / (1.0f + __expf(-x));
    lD1[t] = sg;
    lD2[t] = 1.0f - sg;
    return;
  }
  const int w = tid >> 6;         // wave 0..3
  const int l = tid & 63;         // lane
  const int t0 = bid * 16;
  const int a0 = w * 16;
  const int lr15 = l & 15;
  const int g4 = (l >> 4) * 4;    // k-subgroup base within each 16-half
  const uint32_t* d1p = d1c + (size_t)(t0 + lr15) * U_ + g4;
  const uint32_t* d2p = d2c + (size_t)(t0 + lr15) * U_ + g4;
  const size_t wbase = (size_t)(a0 + lr15) * U_ + g4;
  const uint16_t* w0 = wc + wbase;               // dpr_hi
  f32x4 acc0 = {0.f, 0.f, 0.f, 0.f};  // m1r
  f32x4 acc1 = {0.f, 0.f, 0.f, 0.f};  // m1i
  f32x4 acc2 = {0.f, 0.f, 0.f, 0.f};  // m2r
  f32x4 acc3 = {0.f, 0.f, 0.f, 0.f};  // m2i
  for (int kk = 0; kk < U_; kk += 32) {
    // A-frags: regs 0-1 = k-half [kk, kk+16), regs 2-3 = [kk+16, kk+32)
    const uint4 da = *(const uint4*)(d1p + kk);
    const uint4 db = *(const uint4*)(d1p + kk + 16);
    F8 fr1, fi1, f1n;
    fr1.u[0] = (da.x & 0xffffu) | (da.y << 16);
    fr1.u[1] = (da.z & 0xffffu) | (da.w << 16);
    fr1.u[2] = (db.x & 0xffffu) | (db.y << 16);
    fr1.u[3] = (db.z & 0xffffu) | (db.w << 16);
    fi1.u[0] = (da.x >> 16) | (da.y & 0xffff0000u);
    fi1.u[1] = (da.z >> 16) | (da.w & 0xffff0000u);
    fi1.u[2] = (db.x >> 16) | (db.y & 0xffff0000u);
    fi1.u[3] = (db.z >> 16) | (db.w & 0xffff0000u);
    f1n.u[0] = fi1.u[0] ^ 0x80008000u; f1n.u[1] = fi1.u[1] ^ 0x80008000u;
    f1n.u[2] = fi1.u[2] ^ 0x80008000u; f1n.u[3] = fi1.u[3] ^ 0x80008000u;
    const uint4 dc = *(const uint4*)(d2p + kk);
    const uint4 dd = *(const uint4*)(d2p + kk + 16);
    F8 fr2, fi2, f2n;
    fr2.u[0] = (dc.x & 0xffffu) | (dc.y << 16);
    fr2.u[1] = (dc.z & 0xffffu) | (dc.w << 16);
    fr2.u[2] = (dd.x & 0xffffu) | (dd.y << 16);
    fr2.u[3] = (dd.z & 0xffffu) | (dd.w << 16);
    fi2.u[0] = (dc.x >> 16) | (dc.y & 0xffff0000u);
    fi2.u[1] = (dc.z >> 16) | (dc.w & 0xffff0000u);
    fi2.u[2] = (dd.x >> 16) | (dd.y & 0xffff0000u);
    fi2.u[3] = (dd.z >> 16) | (dd.w & 0xffff0000u);
    f2n.u[0] = fi2.u[0] ^ 0x80008000u; f2n.u[1] = fi2.u[1] ^ 0x80008000u;
    f2n.u[2] = fi2.u[2] ^ 0x80008000u; f2n.u[3] = fi2.u[3] ^ 0x80008000u;
    // B-frags: 8 weight arrays (hi/lo x 4 matrices), same two-half layout
    F8 wf[8];
#pragma unroll
    for (int ai = 0; ai < 8; ++ai) {
      const uint16_t* bp = w0 + (size_t)ai * 131072 + kk;
      const uint2 x0 = *(const uint2*)bp;
      const uint2 x1 = *(const uint2*)(bp + 16);
      wf[ai].u[0] = x0.x; wf[ai].u[1] = x0.y;
      wf[ai].u[2] = x1.x; wf[ai].u[3] = x1.y;
    }
    // m1r = d1r*Wr - d1i*Wi ; m1i = d1r*Wi + d1i*Wr (split hi+lo)
    acc0 = MFMA_(fr1, wf[0], acc0); acc0 = MFMA_(fr1, wf[1], acc0);
    acc0 = MFMA_(f1n, wf[2], acc0); acc0 = MFMA_(f1n, wf[3], acc0);
    acc1 = MFMA_(fr1, wf[2], acc1); acc1 = MFMA_(fr1, wf[3], acc1);
    acc1 = MFMA_(fi1, wf[0], acc1); acc1 = MFMA_(fi1, wf[1], acc1);
    acc2 = MFMA_(fr2, wf[4], acc2); acc2 = MFMA_(fr2, wf[5], acc2);
    acc2 = MFMA_(f2n, wf[6], acc2); acc2 = MFMA_(f2n, wf[7], acc2);
    acc3 = MFMA_(fr2, wf[6], acc3); acc3 = MFMA_(fr2, wf[7], acc3);
    acc3 = MFMA_(fi2, wf[4], acc3); acc3 = MFMA_(fi2, wf[5], acc3);
  }
  // C/D layout (m89-verified): col = lane&15 -> a, row = (lane>>4)*4+reg -> t
  const size_t MS = (size_t)T_ * A_;
#pragma unroll
  for (int reg = 0; reg < 4; ++reg) {
    const int t = t0 + (l >> 4) * 4 + reg;
    const size_t o = (size_t)t * A_ + a0 + lr15;
    m[0 * MS + o] = acc0[reg];
    m[1 * MS + o] = acc1[reg];
    m[2 * MS + o] = acc2[reg];
    m[3 * MS + o] = acc3[reg];
  }
}

// ---------------- Epilogue: compact-m + norm ----------------
__global__ __launch_bounds__(256) void k_epi(
    const float* __restrict__ m4, const float* __restrict__ lD1,
    const float* __restrict__ lD2, const float* __restrict__ noise,
    const float* __restrict__ dpbr, const float* __restrict__ dpbi,
    const float* __restrict__ ipbr, const float* __restrict__ ipbi,
    float* __restrict__ nrm) {
  const size_t MS = (size_t)T_ * A_;
  const int gid = blockIdx.x * 256 + threadIdx.x;
  const size_t e0 = (size_t)gid * 4;
  const int t = (int)(e0 >> 6);
  const int a0 = (int)(e0 & 63);
  float m[4][4];
#pragma unroll
  for (int mi = 0; mi < 4; ++mi) {
    const float4 v = *(const float4*)&m4[(size_t)mi * MS + e0];
    m[mi][0] = v.x; m[mi][1] = v.y; m[mi][2] = v.z; m[mi][3] = v.w;
  }
  const float l1 = lD1[t], l2 = lD2[t];
  const float4 nzv = *(const float4*)&noise[e0];
  const float nz[4] = {nzv.x, nzv.y, nzv.z, nzv.w};
  const float4 q1 = *(const float4*)&dpbr[a0];
  const float4 q2 = *(const float4*)&dpbi[a0];
  const float4 q3 = *(const float4*)&ipbr[a0];
  const float4 q4 = *(const float4*)&ipbi[a0];
  const float b1r[4] = {q1.x, q1.y, q1.z, q1.w};
  const float b1i[4] = {q2.x, q2.y, q2.z, q2.w};
  const float b2r[4] = {q3.x, q3.y, q3.z, q3.w};
  const float b2i[4] = {q4.x, q4.y, q4.z, q4.w};
  float res[4];
#pragma unroll
  for (int j = 0; j < 4; ++j) {
    const float dpr = fmaxf(fmaf(l1, m[0][j], b1r[j]), 0.f);
    const float dpi = fmaxf(fmaf(l1, m[1][j], b1i[j]), 0.f);
    const float ipr = fmaxf(fmaf(l2, m[2][j], b2r[j]), 0.f);
    const float ipi = fmaxf(fmaf(l2, m[3][j], b2i[j]), 0.f);
    const float nzs = l2 * (2.f * nz[j] - 1.f);
    const float dr = dpr - ipr - nzs;
    const float di = dpi - ipi;
    res[j] = sqrtf(dr * dr + di * di);
  }
  *(float4*)&nrm[e0] = make_float4(res[0], res[1], res[2], res[3]);
}

// ---------------- Scan + softmax + outputs (parallel, 3 kernels) ----------
__global__ __launch_bounds__(64) void k_scan_part(const float* __restrict__ nrm,
                                                  float* __restrict__ csum) {
  const int c = blockIdx.x;
  const int a = threadIdx.x;
  const int tb = c * 64;
  float run = 0.f;
  for (int i = 0; i < 64; ++i) run += nrm[(size_t)(tb + i) * 64 + a];
  csum[c * 64 + a] = run;
}

__global__ __launch_bounds__(64) void k_scan_mid(const float* __restrict__ csum,
                                                 const float* __restrict__ value,
                                                 float* __restrict__ coff,
                                                 float* __restrict__ out) {
  const int a = threadIdx.x;
  float acc = 0.f;
#pragma unroll
  for (int cc = 0; cc < 64; ++cc) {
    coff[cc * 64 + a] = acc;
    acc += csum[cc * 64 + a];
  }
  const float g = 0.01f * acc;
  float mx = g;
#pragma unroll
  for (int o = 32; o >= 1; o >>= 1) mx = fmaxf(mx, __shfl_xor(mx, o));
  const float e = __expf(g - mx);
  float sm = e;
#pragma unroll
  for (int o = 32; o >= 1; o >>= 1) sm += __shfl_xor(sm, o);
  out[a] = e / sm;
  if (a == 0) out[64] = value[T_ - 1];
}

__global__ __launch_bounds__(64) void k_scan_out(const float* __restrict__ nrm,
                                                 const float* __restrict__ coff,
                                                 float* __restrict__ out) {
  const int c = blockIdx.x;
  const int a = threadIdx.x;
  const int tb = c * 64;
  float off = coff[c * 64 + a];
  float* o65 = out + 65;
  for (int i = 0; i < 64; ++i) {
    off += nrm[(size_t)(tb + i) * 64 + a];
    o65[(size_t)(tb + i) * 64 + a] = 0.01f * off;
  }
}

extern "C" void kernel_launch(void* const* d_in, const int* in_sizes, int n_in,
                              void* d_out, int out_size, void* d_ws,
                              size_t ws_size, hipStream_t stream) {
  const float* state = (const float*)d_in[0];
  const float* phi1 = (const float*)d_in[1];
  const float* phi2 = (const float*)d_in[2];
  const float* noise = (const float*)d_in[3];
  const float* om1 = (const float*)d_in[4];
  const float* om2 = (const float*)d_in[5];
  const float* l1Wr = (const float*)d_in[6];
  const float* l1Wi = (const float*)d_in[7];
  const float* l1br = (const float*)d_in[8];
  const float* l1bi = (const float*)d_in[9];
  const float* dpWr = (const float*)d_in[10];
  const float* dpWi = (const float*)d_in[11];
  const float* dpbr = (const float*)d_in[12];
  const float* dpbi = (const float*)d_in[13];
  const float* ipWr = (const float*)d_in[14];
  const float* ipWi = (const float*)d_in[15];
  const float* ipbr = (const float*)d_in[16];
  const float* ipbi = (const float*)d_in[17];
  const float* cWr = (const float*)d_in[18];
  const float* cWi = (const float*)d_in[19];
  const float* cbr = (const float*)d_in[20];
  const float* cbi = (const float*)d_in[21];
  float* out = (float*)d_out;

  // Workspace (128MB):
  //   during fused: [0,64M) xc | [64M,96M) d1c | [96M,128M) d2c
  //   after fused (xc dead): [0,4M) m4 | [4M,6M) wc (split-bf16 weights)
  //     [16M,17M) nrm | [17M,+16K) value | lD1,lD2,csum,coff after
  char* ws = (char*)d_ws;
  float* xc = (float*)(ws + (size_t)0);
  uint32_t* d1c = (uint32_t*)(ws + (size_t)67108864);
  uint32_t* d2c = (uint32_t*)(ws + (size_t)100663296);
  float* m4 = (float*)(ws + (size_t)0);
  uint16_t* wc = (uint16_t*)(ws + (size_t)4194304);
  float* nrm = (float*)(ws + (size_t)16777216);
  float* value = (float*)(ws + (size_t)17825792);
  float* lD1 = (float*)(ws + (size_t)17825792 + 16384);
  float* lD2 = (float*)(ws + (size_t)17825792 + 32768);
  float* csum = (float*)(ws + (size_t)17825792 + 49152);
  float* coff = (float*)(ws + (size_t)17825792 + 65536);
  uint32_t* flags = (uint32_t*)out;

  hipMemsetAsync(out, 0, 256, stream);  // zero tile flags (stream-ordered)
  k_fused<<<64 + (T_ / 64) * (U_ / 64), 256, 0, stream>>>(
      state, l1Wr, l1Wi, l1br, l1bi, phi1, phi2, om1, om2, xc, d1c, d2c,
      flags);
  k_crit_wcvt<<<T_ + 16, 256, 0, stream>>>(d1c, cWr, cWi, cbr, cbi, dpWr,
                                           dpWi, ipWr, ipWi, value, wc);
  k_gemmDm_ld<<<256 + 16, 256, 0, stream>>>(d1c, d2c, wc, value, m4, lD1,
                                            lD2);
  k_epi<<<256, 256, 0, stream>>>(m4, lD1, lD2, noise, dpbr, dpbi, ipbr, ipbi,
                                 nrm);
  k_scan_part<<<64, 64, 0, stream>>>(nrm, csum);
  k_scan_mid<<<1, 64, 0, stream>>>(csum, value, coff, out);
  k_scan_out<<<64, 64, 0, stream>>>(nrm, coff, out);
}

// Round 18
// 465.014 us; speedup vs baseline: 1.1684x; 1.1684x over previous
//
#include <hip/hip_runtime.h>
#include <hip/hip_bf16.h>
#include <string.h>
#include <stdint.h>

// Pipeline:
//   k_fused    : gemm1+hopf producer/consumer (R14/R15 PROVEN, verbatim)
//   k_crit_wcvt: critic (4096 blks) + weight split-bf16 -> FRAGMENT-ORDER
//                swizzled conversion (16 blks)
//   k_gemmDm_ld: MFMA gemmD (256 blks; LDS-staged d, coalesced frag weights)
//                + lD (16 blks)
//   k_epi      : compact-m indexing
//   k_scan_*   : unchanged
//
// Ledger (razor-margin test: passing absmax 1.25 vs threshold 1.27):
//   R3 hopf 212us; gemm1->hopf recursion numerics BIT-FROZEN (chaotic).
//   R14/R15: fused gemm1+hopf 304-311us; total 504-512 PASSED.
//   R17: MFMA gemmD PASSED 1.25 (fragment layouts + split-bf16 VALIDATED)
//     but ~185us — slower than the 150us VALU version: per-lane 16B loads
//     at 8KB row stride (uncoalesced), weights re-read scattered (~512MB
//     through thrashed L1), d re-loaded 4x/block. 99% data movement.
//   R18 (this): SAME MFMA input values, proper movement:
//     (a) wcvt writes weights PRE-SWIZZLED into fragment order:
//         frag_idx=((ai*4+strip)*64+chunk), lane l's 16B at frag*1024+l*16
//         -> inner loop = 1 coalesced 1KB load per wave per array, L2-hot.
//     (b) d staged via LDS (16x32 x2, pad 36): coalesced 128B-row global
//         loads, fragments via ds_read_b128. Values bit-identical to R17.
//   Fallback: fail or >510us => revert to R15.

#define T_ 4096
#define D_ 256
#define U_ 2048
#define A_ 64

typedef float f32x4 __attribute__((ext_vector_type(4)));
typedef short bh8 __attribute__((ext_vector_type(8)));
union F8 { uint32_t u[4]; bh8 v; };

__device__ __forceinline__ float bflo(uint32_t p) { return __uint_as_float(p << 16); }
__device__ __forceinline__ float bfhi(uint32_t p) { return __uint_as_float(p & 0xffff0000u); }
__device__ __forceinline__ uint16_t bf16rne(float x) {
  __hip_bfloat16 h = __float2bfloat16(x);
  uint16_t u;
  __builtin_memcpy(&u, &h, 2);
  return u;
}

// ---------------- Hopf step/load macros (R3 structure, PROVEN) -----------
#define HOPF_LOAD(BUF, i, tbase)                                            \
  do {                                                                      \
    const float* bx_ = xc + (size_t)((tbase) + (i)) * (U_ * 2);             \
    asm volatile("global_load_dwordx2 %0, %1, %2"                           \
                 : "=v"(BUF[i])                                             \
                 : "v"(voffx), "s"(bx_));                                   \
  } while (0)

#define HOPF_STEP(BUF, i, tb)                                               \
  do {                                                                      \
    const float xr_ = BUF[i].x, xi_ = BUF[i].y;                             \
    const float f_ = fmaf(xr_, c, xi_ * s);                                 \
    const float g_ = fmaf(xi_, c, -(xr_ * s));                              \
    const float rn_ = fmaf(0.01f, fmaf(r, fmaf(-r, r, 1.0f), f_), r);       \
    const float rinv_ = __builtin_amdgcn_rcpf(fmaxf(r, 1e-6f));             \
    const float phin_ = fmaf(0.01f, g_ * rinv_, phi + dto);                 \
    float cn_, sn_;                                                         \
    __sincosf(phin_, &sn_, &cn_);                                           \
    uint32_t pk_;                                                           \
    asm("v_cvt_pk_bf16_f32 %0, %1, %2"                                     \
        : "=v"(pk_)                                                         \
        : "v"(rn_ * cn_), "v"(rn_ * sn_));                                  \
    const uint32_t* bd_ = dst + (size_t)((tb) + (i)) * U_;                  \
    asm volatile("global_store_dword %0, %1, %2" ::"v"(voffd), "v"(pk_),    \
                 "s"(bd_));                                                  \
    r = rn_; phi = phin_; c = cn_; s = sn_;                                 \
  } while (0)

#define VMWAIT(N)                                  \
  asm volatile("s_waitcnt vmcnt(" #N ")");         \
  __builtin_amdgcn_sched_barrier(0)

#define WAIT_TILE(tt)                                                       \
  do {                                                                      \
    uint32_t rdy_;                                                          \
    for (;;) {                                                              \
      rdy_ = 0u;                                                            \
      if (threadIdx.x == 0)                                                 \
        rdy_ = __hip_atomic_fetch_add(&flags[tt], 0u, __ATOMIC_RELAXED,     \
                                      __HIP_MEMORY_SCOPE_AGENT);            \
      rdy_ = __shfl(rdy_, 0);                                               \
      if (rdy_ >= 32u) break;                                               \
      __builtin_amdgcn_s_sleep(8);                                          \
    }                                                                       \
    __builtin_amdgcn_sched_barrier(0);                                      \
  } while (0)

// ---------------- FUSED gemm1 + hopf (R15 verbatim, PROVEN) --------------
__global__ __launch_bounds__(256) void k_fused(
    const float* __restrict__ S, const float* __restrict__ Wr,
    const float* __restrict__ Wi, const float* __restrict__ br,
    const float* __restrict__ bi, const float* __restrict__ phi1,
    const float* __restrict__ phi2, const float* __restrict__ om1,
    const float* __restrict__ om2, float* __restrict__ xc,
    uint32_t* __restrict__ d1c, uint32_t* __restrict__ d2c,
    uint32_t* __restrict__ flags) {
  const int bid = blockIdx.x;
  if (bid >= 64) {
    __shared__ float sT[32][68];
    __shared__ float wrT[32][68];
    __shared__ float wiT[32][68];
    const int tid = threadIdx.x;
    const int gb = bid - 64;
    const int t0 = (gb >> 5) * 64;
    const int u0 = (gb & 31) * 64;
    const int un = tid & 15, tm = tid >> 4;
    const int lr = tid >> 3;
    const int lc = (tid & 7) * 4;
    float accR[4][4] = {}, accI[4][4] = {};
    for (int k0 = 0; k0 < D_; k0 += 32) {
      __syncthreads();
#pragma unroll
      for (int p = 0; p < 2; ++p) {
        const int row = p * 32 + lr;
        float4 v = *(const float4*)&S[(size_t)(t0 + row) * D_ + k0 + lc];
        sT[lc + 0][row] = v.x; sT[lc + 1][row] = v.y;
        sT[lc + 2][row] = v.z; sT[lc + 3][row] = v.w;
        float4 a = *(const float4*)&Wr[(size_t)(u0 + row) * D_ + k0 + lc];
        wrT[lc + 0][row] = a.x; wrT[lc + 1][row] = a.y;
        wrT[lc + 2][row] = a.z; wrT[lc + 3][row] = a.w;
        float4 b = *(const float4*)&Wi[(size_t)(u0 + row) * D_ + k0 + lc];
        wiT[lc + 0][row] = b.x; wiT[lc + 1][row] = b.y;
        wiT[lc + 2][row] = b.z; wiT[lc + 3][row] = b.w;
      }
      __syncthreads();
#pragma unroll
      for (int k = 0; k < 32; ++k) {
        const float4 sv = *(const float4*)&sT[k][tm * 4];
        const float4 ar = *(const float4*)&wrT[k][un * 4];
        const float4 ai = *(const float4*)&wiT[k][un * 4];
        const float ss[4] = {sv.x, sv.y, sv.z, sv.w};
        const float wd[4] = {ar.x - ai.x, ar.y - ai.y, ar.z - ai.z, ar.w - ai.w};
        const float wm[4] = {ar.x + ai.x, ar.y + ai.y, ar.z + ai.z, ar.w + ai.w};
#pragma unroll
        for (int i = 0; i < 4; ++i)
#pragma unroll
          for (int j = 0; j < 4; ++j) {
            accR[i][j] = fmaf(ss[i], wd[j], accR[i][j]);
            accI[i][j] = fmaf(ss[i], wm[j], accI[i][j]);
          }
      }
    }
    const float4 brv = *(const float4*)&br[u0 + un * 4];
    const float4 biv = *(const float4*)&bi[u0 + un * 4];
    const float brx[4] = {brv.x, brv.y, brv.z, brv.w};
    const float bix[4] = {biv.x, biv.y, biv.z, biv.w};
#pragma unroll
    for (int i = 0; i < 4; ++i) {
      float vr[4], vi[4];
#pragma unroll
      for (int j = 0; j < 4; ++j) {
        vr[j] = fmaxf(accR[i][j] + brx[j], 0.f);
        vi[j] = fmaxf(accI[i][j] + bix[j], 0.f);
      }
      const size_t base = ((size_t)(t0 + tm * 4 + i) * U_ + u0 + un * 4) * 2;
      f32x4 lo = {vr[0], vi[0], vr[1], vi[1]};
      f32x4 hi = {vr[2], vi[2], vr[3], vi[3]};
      float* p0 = &xc[base];
      float* p1 = &xc[base + 4];
      asm volatile("global_store_dwordx4 %0, %1, off sc1" ::"v"(p0), "v"(lo)
                   : "memory");
      asm volatile("global_store_dwordx4 %0, %1, off sc1" ::"v"(p1), "v"(hi)
                   : "memory");
    }
    asm volatile("s_waitcnt vmcnt(0)");
    __syncthreads();
    if (tid == 0)
      __hip_atomic_fetch_add(&flags[t0 >> 6], 1u, __ATOMIC_RELAXED,
                             __HIP_MEMORY_SCOPE_AGENT);
    return;
  }
  if (threadIdx.x >= 64) return;
  __builtin_amdgcn_s_setprio(3);
  const int ub = bid & 31;
  const int osc = bid >> 5;
  const int u = ub * 64 + threadIdx.x;
  float phi = (osc ? phi2[u] : phi1[u]) * 0.1f;
  const float omega = osc ? om2[u] : om1[u];
  const uint32_t* __restrict__ dst = (osc ? d2c : d1c);
  const float dto = 0.01f * omega;
  float r = 1.0f;
  float c, s;
  __sincosf(phi, &s, &c);
  const uint32_t voffx = (uint32_t)u * 8u;
  const uint32_t voffd = (uint32_t)u * 4u;

  constexpr int PF = 32;
  float2 bufA[PF], bufB[PF];
  WAIT_TILE(0);
#pragma unroll
  for (int i = 0; i < PF; ++i) HOPF_LOAD(bufA, i, 0);
#pragma unroll
  for (int i = 0; i < PF; ++i) HOPF_LOAD(bufB, i, PF);
  VMWAIT(32);

  for (int t0 = 0; t0 < T_; t0 += 2 * PF) {
#pragma unroll
    for (int i = 0; i < PF; ++i) HOPF_STEP(bufA, i, t0);
    {
      int tp = t0 + 2 * PF;
      if (tp >= T_) tp = 0;
      WAIT_TILE(tp >> 6);
#pragma unroll
      for (int i = 0; i < PF; ++i) HOPF_LOAD(bufA, i, tp);
    }
    VMWAIT(63);
#pragma unroll
    for (int i = 0; i < PF; ++i) HOPF_STEP(bufB, i, t0 + PF);
    {
      int tp = t0 + 3 * PF;
      if (tp >= T_) tp = 0;
#pragma unroll
      for (int i = 0; i < PF; ++i) HOPF_LOAD(bufB, i, tp);
    }
    VMWAIT(63);
  }
  asm volatile("s_waitcnt vmcnt(0)");
  __builtin_amdgcn_s_setprio(0);
}

// ---------------- critic + fragment-order weight conversion ----------------
// wcvt: 16 blocks x 4 waves = 64 waves; 1024 tasks (mi,strip,chunk); each
// task: lane l reads 8 scattered fp32, writes hi-frag and lo-frag 16B each
// at frag-order addresses (coalesced per wave).
__global__ __launch_bounds__(256) void k_crit_wcvt(
    const uint32_t* __restrict__ d1c, const float* __restrict__ cWr,
    const float* __restrict__ cWi, const float* __restrict__ cbr,
    const float* __restrict__ cbi, const float* __restrict__ dpWr,
    const float* __restrict__ dpWi, const float* __restrict__ ipWr,
    const float* __restrict__ ipWi, float* __restrict__ value,
    uint16_t* __restrict__ wc) {
  const int tid = threadIdx.x;
  if (blockIdx.x >= T_) {
    const float* srcs[4] = {dpWr, dpWi, ipWr, ipWi};
    const int wgid = (blockIdx.x - T_) * 4 + (tid >> 6);  // 0..63
    const int l = tid & 63;
    const int lr15 = l & 15;
    const int g4 = (l >> 4) * 4;
    for (int i = 0; i < 16; ++i) {
      const int task = wgid * 16 + i;       // 0..1023
      const int mi = task >> 8;             // 0..3
      const int st = (task >> 6) & 3;       // strip 0..3
      const int ch = task & 63;             // chunk 0..63
      const float* sp = srcs[mi] + (size_t)(st * 16 + lr15) * U_ + ch * 32 + g4;
      float w0 = sp[0], w1 = sp[1], w2 = sp[2], w3 = sp[3];
      float w4 = sp[16], w5 = sp[17], w6 = sp[18], w7 = sp[19];
      const uint16_t h0 = bf16rne(w0), h1 = bf16rne(w1), h2 = bf16rne(w2),
                     h3 = bf16rne(w3), h4 = bf16rne(w4), h5 = bf16rne(w5),
                     h6 = bf16rne(w6), h7 = bf16rne(w7);
      uint4 hv;
      hv.x = (uint32_t)h0 | ((uint32_t)h1 << 16);
      hv.y = (uint32_t)h2 | ((uint32_t)h3 << 16);
      hv.z = (uint32_t)h4 | ((uint32_t)h5 << 16);
      hv.w = (uint32_t)h6 | ((uint32_t)h7 << 16);
      const uint16_t q0 = bf16rne(w0 - __uint_as_float((uint32_t)h0 << 16));
      const uint16_t q1 = bf16rne(w1 - __uint_as_float((uint32_t)h1 << 16));
      const uint16_t q2 = bf16rne(w2 - __uint_as_float((uint32_t)h2 << 16));
      const uint16_t q3 = bf16rne(w3 - __uint_as_float((uint32_t)h3 << 16));
      const uint16_t q4 = bf16rne(w4 - __uint_as_float((uint32_t)h4 << 16));
      const uint16_t q5 = bf16rne(w5 - __uint_as_float((uint32_t)h5 << 16));
      const uint16_t q6 = bf16rne(w6 - __uint_as_float((uint32_t)h6 << 16));
      const uint16_t q7 = bf16rne(w7 - __uint_as_float((uint32_t)h7 << 16));
      uint4 lv;
      lv.x = (uint32_t)q0 | ((uint32_t)q1 << 16);
      lv.y = (uint32_t)q2 | ((uint32_t)q3 << 16);
      lv.z = (uint32_t)q4 | ((uint32_t)q5 << 16);
      lv.w = (uint32_t)q6 | ((uint32_t)q7 << 16);
      const size_t fhi = ((size_t)((2 * mi) * 4 + st) * 64 + ch);
      const size_t flo = ((size_t)((2 * mi + 1) * 4 + st) * 64 + ch);
      *(uint4*)(wc + (fhi << 9) + (l << 3)) = hv;
      *(uint4*)(wc + (flo << 9) + (l << 3)) = lv;
    }
    return;
  }
  const int t = blockIdx.x;
  float vr = 0.f, vi = 0.f;
#pragma unroll
  for (int i = 0; i < 8; ++i) {
    const int uu = i * 256 + tid;
    const uint32_t p = d1c[(size_t)t * U_ + uu];
    const float dr = bflo(p), di = bfhi(p);
    const float wr = cWr[uu], wi = cWi[uu];
    vr = fmaf(dr, wr, fmaf(-di, wi, vr));
    vi = fmaf(dr, wi, fmaf(di, wr, vi));
  }
#pragma unroll
  for (int o = 32; o >= 1; o >>= 1) {
    vr += __shfl_xor(vr, o);
    vi += __shfl_xor(vi, o);
  }
  __shared__ float red[2][4];
  if ((tid & 63) == 0) { red[0][tid >> 6] = vr; red[1][tid >> 6] = vi; }
  __syncthreads();
  if (tid == 0) {
    const float r0 = red[0][0] + red[0][1] + red[0][2] + red[0][3] + cbr[0];
    const float i0 = red[1][0] + red[1][1] + red[1][2] + red[1][3] + cbi[0];
    value[t] = sqrtf(r0 * r0 + i0 * i0);
  }
}

// ---------------- MFMA gemmD v2 (+ lD role) ----------------
// 256 blocks x 256 thr (4 waves); block -> t-tile [16b,16b+16), wave w ->
// a-strip [16w,16w+16). d staged in LDS (coalesced); weights loaded as
// pre-swizzled frags (coalesced 1KB/wave/array). MFMA values == R17 (PASSED).
#define MFMA_(A, B, C) \
  __builtin_amdgcn_mfma_f32_16x16x32_bf16((A).v, (B).v, (C), 0, 0, 0)

__global__ __launch_bounds__(256) void k_gemmDm_ld(
    const uint32_t* __restrict__ d1c, const uint32_t* __restrict__ d2c,
    const uint16_t* __restrict__ wc, const float* __restrict__ value,
    float* __restrict__ m, float* __restrict__ lD1,
    float* __restrict__ lD2) {
  const int tid = threadIdx.x;
  const int bid = blockIdx.x;
  if (bid >= 256) {
    const int t = (bid - 256) * 256 + tid;
    const float v = value[t];
    const float pv = (t > 0) ? value[t - 1] : 0.f;
    const float x = 5.0f * (v - pv);
    const float sg = 1.0f / (1.0f + __expf(-x));
    lD1[t] = sg;
    lD2[t] = 1.0f - sg;
    return;
  }
  __shared__ __align__(16) uint32_t d1T[16][36];
  __shared__ __align__(16) uint32_t d2T[16][36];
  const int w = tid >> 6;
  const int l = tid & 63;
  const int t0 = bid * 16;
  const int a0 = w * 16;
  const int lr15 = l & 15;
  const int g4 = (l >> 4) * 4;
  // staging role split: threads 0..127 -> d1, 128..255 -> d2
  const int sid = tid & 127;
  const int srow = sid >> 3;        // 0..15
  const int scol = (sid & 7) * 4;   // 0..28
  const uint32_t* sbase = (tid < 128 ? d1c : d2c) + (size_t)(t0 + srow) * U_ + scol;
  f32x4 acc0 = {0.f, 0.f, 0.f, 0.f};
  f32x4 acc1 = {0.f, 0.f, 0.f, 0.f};
  f32x4 acc2 = {0.f, 0.f, 0.f, 0.f};
  f32x4 acc3 = {0.f, 0.f, 0.f, 0.f};
  for (int kk = 0; kk < U_; kk += 32) {
    __syncthreads();
    {
      const uint4 v = *(const uint4*)(sbase + kk);
      uint32_t(*dT)[36] = (tid < 128) ? d1T : d2T;
      dT[srow][scol + 0] = v.x; dT[srow][scol + 1] = v.y;
      dT[srow][scol + 2] = v.z; dT[srow][scol + 3] = v.w;
    }
    __syncthreads();
    // d frags from LDS — identical values to R17's global loads
    const uint4 da = *(const uint4*)&d1T[lr15][g4];
    const uint4 db = *(const uint4*)&d1T[lr15][16 + g4];
    F8 fr1, fi1, f1n;
    fr1.u[0] = (da.x & 0xffffu) | (da.y << 16);
    fr1.u[1] = (da.z & 0xffffu) | (da.w << 16);
    fr1.u[2] = (db.x & 0xffffu) | (db.y << 16);
    fr1.u[3] = (db.z & 0xffffu) | (db.w << 16);
    fi1.u[0] = (da.x >> 16) | (da.y & 0xffff0000u);
    fi1.u[1] = (da.z >> 16) | (da.w & 0xffff0000u);
    fi1.u[2] = (db.x >> 16) | (db.y & 0xffff0000u);
    fi1.u[3] = (db.z >> 16) | (db.w & 0xffff0000u);
    f1n.u[0] = fi1.u[0] ^ 0x80008000u; f1n.u[1] = fi1.u[1] ^ 0x80008000u;
    f1n.u[2] = fi1.u[2] ^ 0x80008000u; f1n.u[3] = fi1.u[3] ^ 0x80008000u;
    const uint4 dc = *(const uint4*)&d2T[lr15][g4];
    const uint4 dd = *(const uint4*)&d2T[lr15][16 + g4];
    F8 fr2, fi2, f2n;
    fr2.u[0] = (dc.x & 0xffffu) | (dc.y << 16);
    fr2.u[1] = (dc.z & 0xffffu) | (dc.w << 16);
    fr2.u[2] = (dd.x & 0xffffu) | (dd.y << 16);
    fr2.u[3] = (dd.z & 0xffffu) | (dd.w << 16);
    fi2.u[0] = (dc.x >> 16) | (dc.y & 0xffff0000u);
    fi2.u[1] = (dc.z >> 16) | (dc.w & 0xffff0000u);
    fi2.u[2] = (dd.x >> 16) | (dd.y & 0xffff0000u);
    fi2.u[3] = (dd.z >> 16) | (dd.w & 0xffff0000u);
    f2n.u[0] = fi2.u[0] ^ 0x80008000u; f2n.u[1] = fi2.u[1] ^ 0x80008000u;
    f2n.u[2] = fi2.u[2] ^ 0x80008000u; f2n.u[3] = fi2.u[3] ^ 0x80008000u;
    // weight frags: coalesced 16B/lane from pre-swizzled wc
    F8 wf[8];
    const int ch = kk >> 5;
#pragma unroll
    for (int ai = 0; ai < 8; ++ai) {
      const uint4 x =
          *(const uint4*)(wc + (((size_t)(ai * 4 + w) * 64 + ch) << 9) +
                          (l << 3));
      wf[ai].u[0] = x.x; wf[ai].u[1] = x.y;
      wf[ai].u[2] = x.z; wf[ai].u[3] = x.w;
    }
    acc0 = MFMA_(fr1, wf[0], acc0); acc0 = MFMA_(fr1, wf[1], acc0);
    acc0 = MFMA_(f1n, wf[2], acc0); acc0 = MFMA_(f1n, wf[3], acc0);
    acc1 = MFMA_(fr1, wf[2], acc1); acc1 = MFMA_(fr1, wf[3], acc1);
    acc1 = MFMA_(fi1, wf[0], acc1); acc1 = MFMA_(fi1, wf[1], acc1);
    acc2 = MFMA_(fr2, wf[4], acc2); acc2 = MFMA_(fr2, wf[5], acc2);
    acc2 = MFMA_(f2n, wf[6], acc2); acc2 = MFMA_(f2n, wf[7], acc2);
    acc3 = MFMA_(fr2, wf[6], acc3); acc3 = MFMA_(fr2, wf[7], acc3);
    acc3 = MFMA_(fi2, wf[4], acc3); acc3 = MFMA_(fi2, wf[5], acc3);
  }
  const size_t MS = (size_t)T_ * A_;
#pragma unroll
  for (int reg = 0; reg < 4; ++reg) {
    const int t = t0 + (l >> 4) * 4 + reg;
    const size_t o = (size_t)t * A_ + a0 + lr15;
    m[0 * MS + o] = acc0[reg];
    m[1 * MS + o] = acc1[reg];
    m[2 * MS + o] = acc2[reg];
    m[3 * MS + o] = acc3[reg];
  }
}

// ---------------- Epilogue: compact-m + norm ----------------
__global__ __launch_bounds__(256) void k_epi(
    const float* __restrict__ m4, const float* __restrict__ lD1,
    const float* __restrict__ lD2, const float* __restrict__ noise,
    const float* __restrict__ dpbr, const float* __restrict__ dpbi,
    const float* __restrict__ ipbr, const float* __restrict__ ipbi,
    float* __restrict__ nrm) {
  const size_t MS = (size_t)T_ * A_;
  const int gid = blockIdx.x * 256 + threadIdx.x;
  const size_t e0 = (size_t)gid * 4;
  const int t = (int)(e0 >> 6);
  const int a0 = (int)(e0 & 63);
  float m[4][4];
#pragma unroll
  for (int mi = 0; mi < 4; ++mi) {
    const float4 v = *(const float4*)&m4[(size_t)mi * MS + e0];
    m[mi][0] = v.x; m[mi][1] = v.y; m[mi][2] = v.z; m[mi][3] = v.w;
  }
  const float l1 = lD1[t], l2 = lD2[t];
  const float4 nzv = *(const float4*)&noise[e0];
  const float nz[4] = {nzv.x, nzv.y, nzv.z, nzv.w};
  const float4 q1 = *(const float4*)&dpbr[a0];
  const float4 q2 = *(const float4*)&dpbi[a0];
  const float4 q3 = *(const float4*)&ipbr[a0];
  const float4 q4 = *(const float4*)&ipbi[a0];
  const float b1r[4] = {q1.x, q1.y, q1.z, q1.w};
  const float b1i[4] = {q2.x, q2.y, q2.z, q2.w};
  const float b2r[4] = {q3.x, q3.y, q3.z, q3.w};
  const float b2i[4] = {q4.x, q4.y, q4.z, q4.w};
  float res[4];
#pragma unroll
  for (int j = 0; j < 4; ++j) {
    const float dpr = fmaxf(fmaf(l1, m[0][j], b1r[j]), 0.f);
    const float dpi = fmaxf(fmaf(l1, m[1][j], b1i[j]), 0.f);
    const float ipr = fmaxf(fmaf(l2, m[2][j], b2r[j]), 0.f);
    const float ipi = fmaxf(fmaf(l2, m[3][j], b2i[j]), 0.f);
    const float nzs = l2 * (2.f * nz[j] - 1.f);
    const float dr = dpr - ipr - nzs;
    const float di = dpi - ipi;
    res[j] = sqrtf(dr * dr + di * di);
  }
  *(float4*)&nrm[e0] = make_float4(res[0], res[1], res[2], res[3]);
}

// ---------------- Scan + softmax + outputs (parallel, 3 kernels) ----------
__global__ __launch_bounds__(64) void k_scan_part(const float* __restrict__ nrm,
                                                  float* __restrict__ csum) {
  const int c = blockIdx.x;
  const int a = threadIdx.x;
  const int tb = c * 64;
  float run = 0.f;
  for (int i = 0; i < 64; ++i) run += nrm[(size_t)(tb + i) * 64 + a];
  csum[c * 64 + a] = run;
}

__global__ __launch_bounds__(64) void k_scan_mid(const float* __restrict__ csum,
                                                 const float* __restrict__ value,
                                                 float* __restrict__ coff,
                                                 float* __restrict__ out) {
  const int a = threadIdx.x;
  float acc = 0.f;
#pragma unroll
  for (int cc = 0; cc < 64; ++cc) {
    coff[cc * 64 + a] = acc;
    acc += csum[cc * 64 + a];
  }
  const float g = 0.01f * acc;
  float mx = g;
#pragma unroll
  for (int o = 32; o >= 1; o >>= 1) mx = fmaxf(mx, __shfl_xor(mx, o));
  const float e = __expf(g - mx);
  float sm = e;
#pragma unroll
  for (int o = 32; o >= 1; o >>= 1) sm += __shfl_xor(sm, o);
  out[a] = e / sm;
  if (a == 0) out[64] = value[T_ - 1];
}

__global__ __launch_bounds__(64) void k_scan_out(const float* __restrict__ nrm,
                                                 const float* __restrict__ coff,
                                                 float* __restrict__ out) {
  const int c = blockIdx.x;
  const int a = threadIdx.x;
  const int tb = c * 64;
  float off = coff[c * 64 + a];
  float* o65 = out + 65;
  for (int i = 0; i < 64; ++i) {
    off += nrm[(size_t)(tb + i) * 64 + a];
    o65[(size_t)(tb + i) * 64 + a] = 0.01f * off;
  }
}

extern "C" void kernel_launch(void* const* d_in, const int* in_sizes, int n_in,
                              void* d_out, int out_size, void* d_ws,
                              size_t ws_size, hipStream_t stream) {
  const float* state = (const float*)d_in[0];
  const float* phi1 = (const float*)d_in[1];
  const float* phi2 = (const float*)d_in[2];
  const float* noise = (const float*)d_in[3];
  const float* om1 = (const float*)d_in[4];
  const float* om2 = (const float*)d_in[5];
  const float* l1Wr = (const float*)d_in[6];
  const float* l1Wi = (const float*)d_in[7];
  const float* l1br = (const float*)d_in[8];
  const float* l1bi = (const float*)d_in[9];
  const float* dpWr = (const float*)d_in[10];
  const float* dpWi = (const float*)d_in[11];
  const float* dpbr = (const float*)d_in[12];
  const float* dpbi = (const float*)d_in[13];
  const float* ipWr = (const float*)d_in[14];
  const float* ipWi = (const float*)d_in[15];
  const float* ipbr = (const float*)d_in[16];
  const float* ipbi = (const float*)d_in[17];
  const float* cWr = (const float*)d_in[18];
  const float* cWi = (const float*)d_in[19];
  const float* cbr = (const float*)d_in[20];
  const float* cbi = (const float*)d_in[21];
  float* out = (float*)d_out;

  // Workspace (128MB):
  //   during fused: [0,64M) xc | [64M,96M) d1c | [96M,128M) d2c
  //   after fused (xc dead): [0,4M) m4 | [4M,6M) wc (frag-order weights)
  //     [16M,17M) nrm | [17M,+16K) value | lD1,lD2,csum,coff after
  char* ws = (char*)d_ws;
  float* xc = (float*)(ws + (size_t)0);
  uint32_t* d1c = (uint32_t*)(ws + (size_t)67108864);
  uint32_t* d2c = (uint32_t*)(ws + (size_t)100663296);
  float* m4 = (float*)(ws + (size_t)0);
  uint16_t* wc = (uint16_t*)(ws + (size_t)4194304);
  float* nrm = (float*)(ws + (size_t)16777216);
  float* value = (float*)(ws + (size_t)17825792);
  float* lD1 = (float*)(ws + (size_t)17825792 + 16384);
  float* lD2 = (float*)(ws + (size_t)17825792 + 32768);
  float* csum = (float*)(ws + (size_t)17825792 + 49152);
  float* coff = (float*)(ws + (size_t)17825792 + 65536);
  uint32_t* flags = (uint32_t*)out;

  hipMemsetAsync(out, 0, 256, stream);  // zero tile flags (stream-ordered)
  k_fused<<<64 + (T_ / 64) * (U_ / 64), 256, 0, stream>>>(
      state, l1Wr, l1Wi, l1br, l1bi, phi1, phi2, om1, om2, xc, d1c, d2c,
      flags);
  k_crit_wcvt<<<T_ + 16, 256, 0, stream>>>(d1c, cWr, cWi, cbr, cbi, dpWr,
                                           dpWi, ipWr, ipWi, value, wc);
  k_gemmDm_ld<<<256 + 16, 256, 0, stream>>>(d1c, d2c, wc, value, m4, lD1,
                                            lD2);
  k_epi<<<256, 256, 0, stream>>>(m4, lD1, lD2, noise, dpbr, dpbi, ipbr, ipbi,
                                 nrm);
  k_scan_part<<<64, 64, 0, stream>>>(nrm, csum);
  k_scan_mid<<<1, 64, 0, stream>>>(csum, value, coff, out);
  k_scan_out<<<64, 64, 0, stream>>>(nrm, coff, out);
}